// Round 6
// baseline (2025.490 us; speedup 1.0000x reference)
//
#include <hip/hip_runtime.h>
#include <math.h>

#define N_NODES 1200000
#define N_EDGES 12000000
#define D_IN    10
#define D_H     20
#define D_ENCC  5
#define VECC    6
#define B_ROWS  200000

#define NBUCK   2048
#define BNODES  586                              // ceil(N_NODES / NBUCK)
#define EPB     16384                            // edges per tile
#define NBLK_E  ((N_EDGES + EPB - 1) / EPB)      // 733
#define CAP     8192                             // LDS staging capacity (bucket cnt ~5860, 30 sigma)
#define PADX    16                               // xs row = 16 floats (64 B, 1 sector)
#define PADH    8                                // hs2 row = 8 floats (32 B)
#define ACCS    11                               // acc stride (odd: all 32 banks covered)

__device__ __forceinline__ float gelu_exact(float x) {
    return 0.5f * x * (1.0f + erff(x * 0.70710678118654752f));
}

// ---- pass 1: coarse bucket histogram + per-tile hist row -----------------
__global__ void k_bhist(const int* __restrict__ dst, int* __restrict__ gcount,
                        int* __restrict__ hist) {
    __shared__ int h[NBUCK];
    for (int t = threadIdx.x; t < NBUCK; t += 256) h[t] = 0;
    __syncthreads();
    long e0 = (long)blockIdx.x * EPB;
    for (int k = 0; k < EPB / 256; k++) {
        long e = e0 + threadIdx.x + k * 256;
        if (e < N_EDGES) atomicAdd(&h[dst[e] / BNODES], 1);
    }
    __syncthreads();
    size_t row = (size_t)blockIdx.x * NBUCK;
    for (int t = threadIdx.x; t < NBUCK; t += 256) {
        int c = h[t];
        hist[row + t] = c;
        if (c) atomicAdd(&gcount[t], c);
    }
}

// ---- pass 2: scan bucket counts (single block) ---------------------------
__global__ void k_bscan(const int* __restrict__ gcount, int* __restrict__ bstart,
                        int* __restrict__ bcursor) {
    __shared__ int ls[NBUCK];
    __shared__ int ps[256];
    int tid = threadIdx.x;
    for (int t = tid; t < NBUCK; t += 256) ls[t] = gcount[t];
    __syncthreads();
    int s = 0;
#pragma unroll
    for (int k = 0; k < NBUCK / 256; k++) s += ls[tid * (NBUCK / 256) + k];
    ps[tid] = s;
    __syncthreads();
    for (int off = 1; off < 256; off <<= 1) {
        int v = (tid >= off) ? ps[tid - off] : 0;
        __syncthreads();
        ps[tid] += v;
        __syncthreads();
    }
    int run = ps[tid] - s;
#pragma unroll
    for (int k = 0; k < NBUCK / 256; k++) {
        int idx = tid * (NBUCK / 256) + k;
        int c = ls[idx];
        bstart[idx] = run;
        bcursor[idx] = run;
        run += c;
    }
    if (tid == 255) bstart[NBUCK] = N_EDGES;
}

// ---- pass 3: tile-sort scatter — coalesced bucket-partitioned writes -----
__global__ __launch_bounds__(1024, 1)
void k_bscatter(const int* __restrict__ src, const int* __restrict__ dst,
                const int* __restrict__ hist, int* __restrict__ bcursor,
                unsigned int* __restrict__ epack) {
    __shared__ unsigned int sdata[EPB];          // 64 KB
    __shared__ unsigned short sbk[EPB];          // 32 KB: bucket id per slot
    __shared__ int h[NBUCK];                     // rank cursors
    __shared__ int lstart[NBUCK];
    __shared__ int gbase[NBUCK];
    __shared__ int ps[1024];
    int tid = threadIdx.x;
    long e0 = (long)blockIdx.x * EPB;
    int cnt = (N_EDGES - e0 < EPB) ? (int)(N_EDGES - e0) : EPB;

    size_t row = (size_t)blockIdx.x * NBUCK;
    int c0 = hist[row + 2 * tid];
    int c1 = hist[row + 2 * tid + 1];
    int s = c0 + c1;
    ps[tid] = s;
    __syncthreads();
    for (int off = 1; off < 1024; off <<= 1) {
        int v = (tid >= off) ? ps[tid - off] : 0;
        __syncthreads();
        ps[tid] += v;
        __syncthreads();
    }
    int run = ps[tid] - s;   // exclusive prefix
    lstart[2 * tid]     = run;
    lstart[2 * tid + 1] = run + c0;
    gbase[2 * tid]     = c0 ? atomicAdd(&bcursor[2 * tid], c0) : 0;
    gbase[2 * tid + 1] = c1 ? atomicAdd(&bcursor[2 * tid + 1], c1) : 0;
    h[2 * tid] = 0;
    h[2 * tid + 1] = 0;
    __syncthreads();

    // rank + place sorted-by-bucket in LDS; record bucket id per slot
    for (int k = 0; k < EPB / 1024; k++) {
        long e = e0 + tid + k * 1024;
        if (e < N_EDGES) {
            int d = dst[e];
            int b = d / BNODES;
            unsigned int rec = ((unsigned int)(d - b * BNODES) << 21) |
                               (unsigned int)src[e];
            int r = atomicAdd(&h[b], 1);
            int slot = lstart[b] + r;
            sdata[slot] = rec;
            sbk[slot] = (unsigned short)b;
        }
    }
    __syncthreads();

    // stream out: consecutive positions -> consecutive global addresses
    for (int p = tid; p < cnt; p += 1024) {
        int b = sbk[p];
        epack[(size_t)gbase[b] + (p - lstart[b])] = sdata[p];
    }
}

// ---- pass 4: per-bucket degrees/dinv/xs + src-radix epack2 (NO CSR) ------
// epack2 records: (src << 10) | dlocal, src-radix-ordered (8K-node bins) so
// the scatter-agg kernels sweep src-space band-locally.
__global__ void k_bbuild(const unsigned int* __restrict__ epack,
                         const int* __restrict__ bstart,
                         const float* __restrict__ x,
                         unsigned int* __restrict__ epack2,
                         float* __restrict__ dinv, float* __restrict__ xs) {
    __shared__ int sdeg[BNODES];
    __shared__ int ps[256];
    __shared__ unsigned int stage[CAP];   // 32 KB
    __shared__ int hist2[256];
    __shared__ int cur2[256];
    __shared__ float spo[D_IN];
    int b = blockIdx.x, tid = threadIdx.x;
    if (tid < D_IN) spo[tid] = sinf((float)tid);
    hist2[tid] = 0;
    int n0 = b * BNODES;
    int n1 = n0 + BNODES; if (n1 > N_NODES) n1 = N_NODES;
    int nn = n1 - n0;
    int e0 = bstart[b], e1 = bstart[b + 1];
    int cnt = e1 - e0;
    for (int t = tid; t < nn; t += 256) sdeg[t] = 0;
    __syncthreads();
    for (int p = tid; p < cnt; p += 256) {
        unsigned int u = epack[e0 + p];
        atomicAdd(&sdeg[u >> 21], 1);
        atomicAdd(&hist2[(u & 0x1FFFFFu) >> 13], 1);
    }
    __syncthreads();
    // scan hist2 -> cur2 (radix cursors)
    int hv = hist2[tid];
    ps[tid] = hv;
    __syncthreads();
    for (int off = 1; off < 256; off <<= 1) {
        int v = (tid >= off) ? ps[tid - off] : 0;
        __syncthreads();
        ps[tid] += v;
        __syncthreads();
    }
    cur2[tid] = ps[tid] - hv;
    // dinv
    for (int i = tid; i < nn; i += 256)
        dinv[n0 + i] = rsqrtf((float)sdeg[i] + 1.0f);
    __syncthreads();
    if (cnt <= CAP) {
        // radix scatter by src bin into stage, then coalesced write-out
        for (int p = tid; p < cnt; p += 256) {
            unsigned int u = epack[e0 + p];
            int pos = atomicAdd(&cur2[(u & 0x1FFFFFu) >> 13], 1);
            stage[pos] = ((u & 0x1FFFFFu) << 10) | (u >> 21);
        }
        __syncthreads();
        for (int p = tid; p < cnt; p += 256) epack2[e0 + p] = stage[p];
    } else {
        // fallback (statistically never): unsorted passthrough
        for (int p = tid; p < cnt; p += 256) {
            unsigned int u = epack[e0 + p];
            epack2[e0 + p] = ((u & 0x1FFFFFu) << 10) | (u >> 21);
        }
    }
    // xs = (x + po) * dinv, 64B-aligned rows
    for (int p = tid; p < nn * PADX; p += 256) {
        int ln = p >> 4;
        int k  = p & 15;
        float v = 0.f;
        if (k < D_IN)
            v = (x[(size_t)(n0 + ln) * D_IN + k] + spo[k]) *
                rsqrtf((float)sdeg[ln] + 1.0f);
        xs[(size_t)(n0 + ln) * PADX + k] = v;
    }
}

// ---- GCN1: per-bucket LDS scatter-accumulate + fused MLP -----------------
// Anti-spill discipline (round-3 failure was VGPR-256 + 830 MB scratch):
// unroll 1 on the edge loop, launch_bounds caps VGPR at 128; TLP (5
// blocks/CU x 4 waves) provides the memory parallelism instead of ILP.
__global__ __launch_bounds__(256, 4)
void k_agg1(const unsigned int* __restrict__ epack2, const int* __restrict__ bstart,
            const float* __restrict__ xs, const float* __restrict__ dinv,
            const float* __restrict__ W1, const float* __restrict__ b1,
            const float* __restrict__ W2, float* __restrict__ hs2p) {
    __shared__ float acc[BNODES * ACCS];      // 25.8 KB
    __shared__ float sW1[D_IN * D_H];
    __shared__ float sb1[D_H];
    __shared__ float sW2[D_H * D_ENCC];
    int b = blockIdx.x, tid = threadIdx.x;
    for (int t = tid; t < 200; t += 256) sW1[t] = W1[t];
    if (tid < 20) sb1[tid] = b1[tid];
    for (int t = tid; t < 100; t += 256) sW2[t] = W2[t];
    int n0 = b * BNODES;
    int n1 = n0 + BNODES; if (n1 > N_NODES) n1 = N_NODES;
    int nn = n1 - n0;
    // init acc with self contribution xs[i] (coalesced)
    for (int p = tid; p < nn * PADX; p += 256) {
        int ln = p >> 4;
        int k  = p & 15;
        if (k < 10) acc[ln * ACCS + k] = xs[(size_t)n0 * PADX + p];
    }
    __syncthreads();
    int e0 = bstart[b], cnt = bstart[b + 1] - e0;
#pragma unroll 1
    for (int p = tid; p < cnt; p += 256) {
        unsigned int rec = epack2[e0 + p];
        int s  = (int)(rec >> 10);
        int dl = (int)(rec & 1023u);
        const float* row = xs + (size_t)s * PADX;
        float4 a  = *(const float4*)row;
        float4 bb = *(const float4*)(row + 4);
        float2 cc = *(const float2*)(row + 8);
        float* ap = acc + dl * ACCS;
        atomicAdd(ap + 0, a.x);  atomicAdd(ap + 1, a.y);
        atomicAdd(ap + 2, a.z);  atomicAdd(ap + 3, a.w);
        atomicAdd(ap + 4, bb.x); atomicAdd(ap + 5, bb.y);
        atomicAdd(ap + 6, bb.z); atomicAdd(ap + 7, bb.w);
        atomicAdd(ap + 8, cc.x); atomicAdd(ap + 9, cc.y);
    }
    __syncthreads();
    // fused MLP: y = di*acc -> gelu(W1 y + b1) -> W2 -> * di
    for (int n = tid; n < nn; n += 256) {
        float di = dinv[n0 + n];
        float y[10];
#pragma unroll
        for (int k = 0; k < 10; k++) y[k] = di * acc[n * ACCS + k];
        float z0 = 0.f, z1 = 0.f, z2 = 0.f, z3 = 0.f, z4 = 0.f;
#pragma unroll
        for (int j = 0; j < 20; j++) {
            float t = sb1[j];
#pragma unroll
            for (int k = 0; k < 10; k++) t += y[k] * sW1[k * D_H + j];
            float g = gelu_exact(t);
            z0 += g * sW2[j * 5 + 0]; z1 += g * sW2[j * 5 + 1];
            z2 += g * sW2[j * 5 + 2]; z3 += g * sW2[j * 5 + 3];
            z4 += g * sW2[j * 5 + 4];
        }
        float* o = hs2p + (size_t)(n0 + n) * PADH;
        o[0] = di * z0; o[1] = di * z1; o[2] = di * z2;
        o[3] = di * z3; o[4] = di * z4;
    }
}

// ---- GCN2: per-bucket LDS scatter-accumulate + bias + GELU ---------------
__global__ __launch_bounds__(256, 4)
void k_agg2(const unsigned int* __restrict__ epack2, const int* __restrict__ bstart,
            const float* __restrict__ hs2p, const float* __restrict__ dinv,
            const float* __restrict__ b2, float* __restrict__ h2) {
    __shared__ float acc[BNODES * 5];        // 11.7 KB (stride 5: all banks)
    __shared__ float sb2[5];
    int b = blockIdx.x, tid = threadIdx.x;
    if (tid < 5) sb2[tid] = b2[tid];
    int n0 = b * BNODES;
    int n1 = n0 + BNODES; if (n1 > N_NODES) n1 = N_NODES;
    int nn = n1 - n0;
    // init with self contribution (coalesced)
    for (int p = tid; p < nn * PADH; p += 256) {
        int ln = p >> 3;
        int k  = p & 7;
        if (k < 5) acc[ln * 5 + k] = hs2p[(size_t)n0 * PADH + p];
    }
    __syncthreads();
    int e0 = bstart[b], cnt = bstart[b + 1] - e0;
#pragma unroll 1
    for (int p = tid; p < cnt; p += 256) {
        unsigned int rec = epack2[e0 + p];
        int s  = (int)(rec >> 10);
        int dl = (int)(rec & 1023u);
        const float* row = hs2p + (size_t)s * PADH;
        float4 a = *(const float4*)row;
        float  e = row[4];
        float* ap = acc + dl * 5;
        atomicAdd(ap + 0, a.x); atomicAdd(ap + 1, a.y);
        atomicAdd(ap + 2, a.z); atomicAdd(ap + 3, a.w);
        atomicAdd(ap + 4, e);
    }
    __syncthreads();
    for (int n = tid; n < nn; n += 256) {
        float di = dinv[n0 + n];
#pragma unroll
        for (int c = 0; c < 5; c++)
            h2[(size_t)(n0 + n) * 5 + c] = gelu_exact(di * acc[n * 5 + c] + sb2[c]);
    }
}

// ---- dense tail ----------------------------------------------------------
__global__ void k_dense(const float* __restrict__ h2,
                        const float* __restrict__ We, const float* __restrict__ be,
                        const float* __restrict__ Wd, const float* __restrict__ bd,
                        const float* __restrict__ Wr, const float* __restrict__ br,
                        float* __restrict__ out) {
    __shared__ float sWe[900], sWd[1800], sWr[210];
    __shared__ float sbe[30], sbd[60], sbr[7];
    for (int t = threadIdx.x; t < 900;  t += blockDim.x) sWe[t] = We[t];
    for (int t = threadIdx.x; t < 1800; t += blockDim.x) sWd[t] = Wd[t];
    for (int t = threadIdx.x; t < 210;  t += blockDim.x) sWr[t] = Wr[t];
    if (threadIdx.x < 30) sbe[threadIdx.x] = be[threadIdx.x];
    if (threadIdx.x >= 64  && threadIdx.x < 124) sbd[threadIdx.x - 64]  = bd[threadIdx.x - 64];
    if (threadIdx.x >= 128 && threadIdx.x < 135) sbr[threadIdx.x - 128] = br[threadIdx.x - 128];
    __syncthreads();
    int b = blockIdx.x * blockDim.x + threadIdx.x;
    if (b >= B_ROWS) return;

    float r[30];
#pragma unroll
    for (int k = 0; k < 30; k++) r[k] = h2[(size_t)b * 30 + k];

    float enc[30];
#pragma unroll
    for (int j = 0; j < 30; j++) {
        float a = sbe[j];
#pragma unroll
        for (int k = 0; k < 30; k++) a += r[k] * sWe[k * 30 + j];
        enc[j] = a;
    }

    float* x1o  = out;
    float* enco = out + (size_t)B_ROWS * 7;
    float* outo = out + (size_t)B_ROWS * 37;

#pragma unroll
    for (int j = 0; j < 30; j++) enco[(size_t)b * 30 + j] = enc[j];

#pragma unroll
    for (int k = 0; k < 30; k++) r[k] = gelu_exact(enc[k]);
#pragma unroll
    for (int j = 0; j < 60; j++) {
        float a = sbd[j];
#pragma unroll
        for (int k = 0; k < 30; k++) a += r[k] * sWd[k * 60 + j];
        outo[(size_t)b * 60 + j] = a;
    }
#pragma unroll
    for (int j = 0; j < 7; j++) {
        float a = sbr[j];
#pragma unroll
        for (int k = 0; k < 30; k++) a += enc[k] * sWr[k * 7 + j];
        x1o[(size_t)b * 7 + j] = a;
    }
}

extern "C" void kernel_launch(void* const* d_in, const int* in_sizes, int n_in,
                              void* d_out, int out_size, void* d_ws, size_t ws_size,
                              hipStream_t stream) {
    const float* x   = (const float*)d_in[0];
    const int*   ei  = (const int*)d_in[1];
    const int*   src = ei;
    const int*   dst = ei + N_EDGES;
    const float* W1  = (const float*)d_in[2];
    const float* b1  = (const float*)d_in[3];
    const float* W2  = (const float*)d_in[4];
    const float* b2  = (const float*)d_in[5];
    const float* We  = (const float*)d_in[6];
    const float* be  = (const float*)d_in[7];
    const float* Wd  = (const float*)d_in[8];
    const float* bd  = (const float*)d_in[9];
    const float* Wr  = (const float*)d_in[10];
    const float* br  = (const float*)d_in[11];

    char* ws = (char*)d_ws;
    // epack (48 MB) consumed by k_bbuild, then reused as hs2p (38.4 MB).
    unsigned int* epack = (unsigned int*)ws;  ws += sizeof(unsigned int) * (size_t)N_EDGES;
    float* hs2p  = (float*)epack;
    unsigned int* epack2 = (unsigned int*)ws; ws += sizeof(unsigned int) * (size_t)N_EDGES;
    float* dinv   = (float*)ws; ws += sizeof(float) * N_NODES;
    float* xs     = (float*)ws; ws += sizeof(float) * (size_t)N_NODES * PADX;
    float* h2     = (float*)ws; ws += sizeof(float) * (size_t)N_NODES * D_ENCC;
    int*   hist   = (int*)ws;   ws += sizeof(int) * (size_t)NBLK_E * NBUCK;
    int*   gcount = (int*)ws;   ws += sizeof(int) * NBUCK;
    int*   bstart = (int*)ws;   ws += sizeof(int) * (NBUCK + 16);
    int*   bcursor= (int*)ws;   ws += sizeof(int) * NBUCK;

    hipMemsetAsync(gcount, 0, sizeof(int) * NBUCK, stream);

    k_bhist   <<<NBLK_E, 256, 0, stream>>>(dst, gcount, hist);
    k_bscan   <<<1, 256, 0, stream>>>(gcount, bstart, bcursor);
    k_bscatter<<<NBLK_E, 1024, 0, stream>>>(src, dst, hist, bcursor, epack);
    k_bbuild  <<<NBUCK, 256, 0, stream>>>(epack, bstart, x, epack2, dinv, xs);
    k_agg1    <<<NBUCK, 256, 0, stream>>>(epack2, bstart, xs, dinv, W1, b1, W2, hs2p);
    k_agg2    <<<NBUCK, 256, 0, stream>>>(epack2, bstart, hs2p, dinv, b2, h2);
    k_dense   <<<(B_ROWS + 255) / 256, 256, 0, stream>>>(h2, We, be, Wd, bd, Wr, br,
                                                         (float*)d_out);
}

// Round 7
// 907.558 us; speedup vs baseline: 2.2318x; 2.2318x over previous
//
#include <hip/hip_runtime.h>
#include <math.h>

#define N_NODES 1200000
#define N_EDGES 12000000
#define D_IN    10
#define D_H     20
#define D_ENCC  5
#define VECC    6
#define B_ROWS  200000

#define NBUCK   2048
#define BNODES  586                              // ceil(N_NODES / NBUCK)
#define EPB     16384                            // edges per tile
#define NBLK_E  ((N_EDGES + EPB - 1) / EPB)      // 733
#define CAP     8192                             // LDS CSR staging capacity
#define PADX    16                               // xs row = 16 floats (64 B, 1 sector)
#define PADH    8                                // hs2 row = 8 floats (32 B)

__device__ __forceinline__ float gelu_exact(float x) {
    return 0.5f * x * (1.0f + erff(x * 0.70710678118654752f));
}

// ---- pass 1: coarse bucket histogram + per-tile hist row -----------------
__global__ void k_bhist(const int* __restrict__ dst, int* __restrict__ gcount,
                        int* __restrict__ hist) {
    __shared__ int h[NBUCK];
    for (int t = threadIdx.x; t < NBUCK; t += 256) h[t] = 0;
    __syncthreads();
    long e0 = (long)blockIdx.x * EPB;
    for (int k = 0; k < EPB / 256; k++) {
        long e = e0 + threadIdx.x + k * 256;
        if (e < N_EDGES) atomicAdd(&h[dst[e] / BNODES], 1);
    }
    __syncthreads();
    size_t row = (size_t)blockIdx.x * NBUCK;
    for (int t = threadIdx.x; t < NBUCK; t += 256) {
        int c = h[t];
        hist[row + t] = c;
        if (c) atomicAdd(&gcount[t], c);
    }
}

// ---- pass 2: scan bucket counts (single block) ---------------------------
__global__ void k_bscan(const int* __restrict__ gcount, int* __restrict__ bstart,
                        int* __restrict__ bcursor) {
    __shared__ int ls[NBUCK];
    __shared__ int ps[256];
    int tid = threadIdx.x;
    for (int t = tid; t < NBUCK; t += 256) ls[t] = gcount[t];
    __syncthreads();
    int s = 0;
#pragma unroll
    for (int k = 0; k < NBUCK / 256; k++) s += ls[tid * (NBUCK / 256) + k];
    ps[tid] = s;
    __syncthreads();
    for (int off = 1; off < 256; off <<= 1) {
        int v = (tid >= off) ? ps[tid - off] : 0;
        __syncthreads();
        ps[tid] += v;
        __syncthreads();
    }
    int run = ps[tid] - s;
#pragma unroll
    for (int k = 0; k < NBUCK / 256; k++) {
        int idx = tid * (NBUCK / 256) + k;
        int c = ls[idx];
        bstart[idx] = run;
        bcursor[idx] = run;
        run += c;
    }
    if (tid == 255) bstart[NBUCK] = N_EDGES;
}

// ---- pass 3: tile-sort scatter — coalesced bucket-partitioned writes -----
__global__ __launch_bounds__(1024, 1)
void k_bscatter(const int* __restrict__ src, const int* __restrict__ dst,
                const int* __restrict__ hist, int* __restrict__ bcursor,
                unsigned int* __restrict__ epack) {
    __shared__ unsigned int sdata[EPB];          // 64 KB
    __shared__ unsigned short sbk[EPB];          // 32 KB: bucket id per slot
    __shared__ int h[NBUCK];                     // rank cursors
    __shared__ int lstart[NBUCK];
    __shared__ int gbase[NBUCK];
    __shared__ int ps[1024];
    int tid = threadIdx.x;
    long e0 = (long)blockIdx.x * EPB;
    int cnt = (N_EDGES - e0 < EPB) ? (int)(N_EDGES - e0) : EPB;

    size_t row = (size_t)blockIdx.x * NBUCK;
    int c0 = hist[row + 2 * tid];
    int c1 = hist[row + 2 * tid + 1];
    int s = c0 + c1;
    ps[tid] = s;
    __syncthreads();
    for (int off = 1; off < 1024; off <<= 1) {
        int v = (tid >= off) ? ps[tid - off] : 0;
        __syncthreads();
        ps[tid] += v;
        __syncthreads();
    }
    int run = ps[tid] - s;   // exclusive prefix
    lstart[2 * tid]     = run;
    lstart[2 * tid + 1] = run + c0;
    gbase[2 * tid]     = c0 ? atomicAdd(&bcursor[2 * tid], c0) : 0;
    gbase[2 * tid + 1] = c1 ? atomicAdd(&bcursor[2 * tid + 1], c1) : 0;
    h[2 * tid] = 0;
    h[2 * tid + 1] = 0;
    __syncthreads();

    // rank + place sorted-by-bucket in LDS; record bucket id per slot
    for (int k = 0; k < EPB / 1024; k++) {
        long e = e0 + tid + k * 1024;
        if (e < N_EDGES) {
            int d = dst[e];
            int b = d / BNODES;
            unsigned int rec = ((unsigned int)(d - b * BNODES) << 21) |
                               (unsigned int)src[e];
            int r = atomicAdd(&h[b], 1);
            int slot = lstart[b] + r;
            sdata[slot] = rec;
            sbk[slot] = (unsigned short)b;
        }
    }
    __syncthreads();

    // stream out: consecutive positions -> consecutive global addresses
    for (int p = tid; p < cnt; p += 1024) {
        int b = sbk[p];
        epack[(size_t)gbase[b] + (p - lstart[b])] = sdata[p];
    }
}

// ---- pass 4: per-bucket CSR build in LDS + dinv + xs = (x+po)*dinv -------
__global__ void k_bbuild(const unsigned int* __restrict__ epack,
                         const int* __restrict__ bstart,
                         const float* __restrict__ x,
                         int* __restrict__ csr, int* __restrict__ rowptr,
                         float* __restrict__ dinv, float* __restrict__ xs) {
    __shared__ int sdeg[BNODES];
    __shared__ int scur[BNODES];
    __shared__ int ps[256];
    __shared__ int stage[CAP];
    __shared__ float spo[D_IN];
    int b = blockIdx.x, tid = threadIdx.x;
    if (tid < D_IN) spo[tid] = sinf((float)tid);
    int n0 = b * BNODES;
    int n1 = n0 + BNODES; if (n1 > N_NODES) n1 = N_NODES;
    int nn = n1 - n0;
    int e0 = bstart[b], e1 = bstart[b + 1];
    int cnt = e1 - e0;
    for (int t = tid; t < nn; t += 256) sdeg[t] = 0;
    __syncthreads();
    for (int p = tid; p < cnt; p += 256)
        atomicAdd(&sdeg[epack[e0 + p] >> 21], 1);
    __syncthreads();
    int i0 = tid * 3;
    int s = 0;
#pragma unroll
    for (int k = 0; k < 3; k++) { int i = i0 + k; if (i < nn) s += sdeg[i]; }
    ps[tid] = s;
    __syncthreads();
    for (int off = 1; off < 256; off <<= 1) {
        int v = (tid >= off) ? ps[tid - off] : 0;
        __syncthreads();
        ps[tid] += v;
        __syncthreads();
    }
    int run = ps[tid] - s;
#pragma unroll
    for (int k = 0; k < 3; k++) {
        int i = i0 + k;
        if (i < nn) {
            int dg = sdeg[i];
            scur[i] = run;
            rowptr[n0 + i] = e0 + run;
            dinv[n0 + i] = rsqrtf((float)dg + 1.0f);
            run += dg;
        }
    }
    if (b == 0 && tid == 0) rowptr[N_NODES] = N_EDGES;
    __syncthreads();
    for (int p = tid; p < cnt; p += 256) {
        unsigned int u = epack[e0 + p];
        int dl = u >> 21;
        int sv = (int)(u & 0x1FFFFFu);
        int r = atomicAdd(&scur[dl], 1);
        if (r < CAP) stage[r] = sv;
        else         csr[e0 + r] = sv;   // overflow fallback (statistically never)
    }
    __syncthreads();
    int lim = cnt < CAP ? cnt : CAP;
    for (int p = tid; p < lim; p += 256) csr[e0 + p] = stage[p];
    for (int p = tid; p < nn * PADX; p += 256) {
        int ln = p >> 4;
        int k  = p & 15;
        float v = 0.f;
        if (k < D_IN)
            v = (x[(size_t)(n0 + ln) * D_IN + k] + spo[k]) *
                rsqrtf((float)sdeg[ln] + 1.0f);
        xs[(size_t)(n0 + ln) * PADX + k] = v;
    }
}

// ---- GCN1: aggregate 10-dim xs, then fused W1+b1 -> gelu -> W2 -> *dinv --
// Dual-ended gather: two independent 4-deep batches (j forward, k backward)
// keep 8 lines in flight as two chains — engages fully on every row >= 8
// and degrades to 4+scalar instead of serial on tails.
__global__ void k_agg1(const int* __restrict__ rowptr, const int* __restrict__ csr,
                       const float* __restrict__ xs, const float* __restrict__ dinv,
                       const float* __restrict__ W1, const float* __restrict__ b1,
                       const float* __restrict__ W2, float* __restrict__ hs2p) {
    __shared__ float sW1[D_IN * D_H];
    __shared__ float sb1[D_H];
    __shared__ float sW2[D_H * D_ENCC];
    __shared__ float sy[64][10];
    __shared__ float part[320][5];
    int tid = threadIdx.x;
    if      (tid < 200) sW1[tid] = W1[tid];
    else if (tid < 220) sb1[tid - 200] = b1[tid - 200];
    else                sW2[tid - 220] = W2[tid - 220];
    long t = (long)blockIdx.x * 320 + tid;
    bool act = t < (long)N_NODES * 5;
    int i = (int)(t / 5);
    int c = tid % 5;
    int ln = tid / 5;
    float2 acc = make_float2(0.f, 0.f);
    float di = 0.f;
    if (act) {
        const size_t co = (size_t)(c * 2);
        di = dinv[i];
        acc = *(const float2*)(xs + (size_t)i * PADX + co);
        int j = rowptr[i], k = rowptr[i + 1];
        while (k - j >= 8) {
            int s0 = csr[j + 0], s1 = csr[j + 1], s2 = csr[j + 2], s3 = csr[j + 3];
            int s4 = csr[k - 4], s5 = csr[k - 3], s6 = csr[k - 2], s7 = csr[k - 1];
            float2 v0 = *(const float2*)(xs + (size_t)s0 * PADX + co);
            float2 v1 = *(const float2*)(xs + (size_t)s1 * PADX + co);
            float2 v2 = *(const float2*)(xs + (size_t)s2 * PADX + co);
            float2 v3 = *(const float2*)(xs + (size_t)s3 * PADX + co);
            float2 v4 = *(const float2*)(xs + (size_t)s4 * PADX + co);
            float2 v5 = *(const float2*)(xs + (size_t)s5 * PADX + co);
            float2 v6 = *(const float2*)(xs + (size_t)s6 * PADX + co);
            float2 v7 = *(const float2*)(xs + (size_t)s7 * PADX + co);
            acc.x += v0.x + v1.x + v2.x + v3.x + v4.x + v5.x + v6.x + v7.x;
            acc.y += v0.y + v1.y + v2.y + v3.y + v4.y + v5.y + v6.y + v7.y;
            j += 4; k -= 4;
        }
        if (k - j >= 4) {
            int s0 = csr[j + 0], s1 = csr[j + 1], s2 = csr[j + 2], s3 = csr[j + 3];
            float2 v0 = *(const float2*)(xs + (size_t)s0 * PADX + co);
            float2 v1 = *(const float2*)(xs + (size_t)s1 * PADX + co);
            float2 v2 = *(const float2*)(xs + (size_t)s2 * PADX + co);
            float2 v3 = *(const float2*)(xs + (size_t)s3 * PADX + co);
            acc.x += v0.x + v1.x + v2.x + v3.x;
            acc.y += v0.y + v1.y + v2.y + v3.y;
            j += 4;
        }
        for (; j < k; j++) {
            int s = csr[j];
            const float2 v = *(const float2*)(xs + (size_t)s * PADX + co);
            acc.x += v.x; acc.y += v.y;
        }
    }
    __syncthreads();
    sy[ln][c * 2]     = di * acc.x;
    sy[ln][c * 2 + 1] = di * acc.y;
    __syncthreads();
    float y[10];
#pragma unroll
    for (int k = 0; k < 10; k++) y[k] = sy[ln][k];
    float p0 = 0.f, p1 = 0.f, p2 = 0.f, p3 = 0.f, p4 = 0.f;
#pragma unroll
    for (int jj = 0; jj < 4; jj++) {
        int j = c * 4 + jj;
        float tv = sb1[j];
#pragma unroll
        for (int k = 0; k < 10; k++) tv += y[k] * sW1[k * D_H + j];
        float g = gelu_exact(tv);
        p0 += g * sW2[j * 5 + 0]; p1 += g * sW2[j * 5 + 1]; p2 += g * sW2[j * 5 + 2];
        p3 += g * sW2[j * 5 + 3]; p4 += g * sW2[j * 5 + 4];
    }
    part[tid][0] = p0; part[tid][1] = p1; part[tid][2] = p2;
    part[tid][3] = p3; part[tid][4] = p4;
    __syncthreads();
    if (act) {
        int q = ln * 5;
        float sm = part[q][c] + part[q + 1][c] + part[q + 2][c]
                 + part[q + 3][c] + part[q + 4][c];
        hs2p[(size_t)i * PADH + c] = di * sm;
    }
}

// ---- GCN2 gather-aggregate + GELU (dual-ended batching) ------------------
__global__ void k_agg2(const int* __restrict__ rowptr, const int* __restrict__ csr,
                       const float* __restrict__ hs2p, const float* __restrict__ dinv,
                       const float* __restrict__ b2, float* __restrict__ h2) {
    long t = (long)blockIdx.x * blockDim.x + threadIdx.x;
    if (t >= (long)N_NODES * 5) return;
    int i = (int)(t / 5);
    int c = (int)(t % 5);
    float di = dinv[i];
    float acc = hs2p[(size_t)i * PADH + c];
    int j = rowptr[i], k = rowptr[i + 1];
    while (k - j >= 8) {
        int s0 = csr[j + 0], s1 = csr[j + 1], s2 = csr[j + 2], s3 = csr[j + 3];
        int s4 = csr[k - 4], s5 = csr[k - 3], s6 = csr[k - 2], s7 = csr[k - 1];
        float a0 = hs2p[(size_t)s0 * PADH + c];
        float a1 = hs2p[(size_t)s1 * PADH + c];
        float a2 = hs2p[(size_t)s2 * PADH + c];
        float a3 = hs2p[(size_t)s3 * PADH + c];
        float a4 = hs2p[(size_t)s4 * PADH + c];
        float a5 = hs2p[(size_t)s5 * PADH + c];
        float a6 = hs2p[(size_t)s6 * PADH + c];
        float a7 = hs2p[(size_t)s7 * PADH + c];
        acc += a0 + a1 + a2 + a3 + a4 + a5 + a6 + a7;
        j += 4; k -= 4;
    }
    if (k - j >= 4) {
        int s0 = csr[j + 0], s1 = csr[j + 1], s2 = csr[j + 2], s3 = csr[j + 3];
        float a0 = hs2p[(size_t)s0 * PADH + c];
        float a1 = hs2p[(size_t)s1 * PADH + c];
        float a2 = hs2p[(size_t)s2 * PADH + c];
        float a3 = hs2p[(size_t)s3 * PADH + c];
        acc += a0 + a1 + a2 + a3;
        j += 4;
    }
    for (; j < k; j++)
        acc += hs2p[(size_t)csr[j] * PADH + c];
    h2[(size_t)i * 5 + c] = gelu_exact(di * acc + b2[c]);
}

// ---- dense tail ----------------------------------------------------------
__global__ void k_dense(const float* __restrict__ h2,
                        const float* __restrict__ We, const float* __restrict__ be,
                        const float* __restrict__ Wd, const float* __restrict__ bd,
                        const float* __restrict__ Wr, const float* __restrict__ br,
                        float* __restrict__ out) {
    __shared__ float sWe[900], sWd[1800], sWr[210];
    __shared__ float sbe[30], sbd[60], sbr[7];
    for (int t = threadIdx.x; t < 900;  t += blockDim.x) sWe[t] = We[t];
    for (int t = threadIdx.x; t < 1800; t += blockDim.x) sWd[t] = Wd[t];
    for (int t = threadIdx.x; t < 210;  t += blockDim.x) sWr[t] = Wr[t];
    if (threadIdx.x < 30) sbe[threadIdx.x] = be[threadIdx.x];
    if (threadIdx.x >= 64  && threadIdx.x < 124) sbd[threadIdx.x - 64]  = bd[threadIdx.x - 64];
    if (threadIdx.x >= 128 && threadIdx.x < 135) sbr[threadIdx.x - 128] = br[threadIdx.x - 128];
    __syncthreads();
    int b = blockIdx.x * blockDim.x + threadIdx.x;
    if (b >= B_ROWS) return;

    float r[30];
#pragma unroll
    for (int k = 0; k < 30; k++) r[k] = h2[(size_t)b * 30 + k];

    float enc[30];
#pragma unroll
    for (int j = 0; j < 30; j++) {
        float a = sbe[j];
#pragma unroll
        for (int k = 0; k < 30; k++) a += r[k] * sWe[k * 30 + j];
        enc[j] = a;
    }

    float* x1o  = out;
    float* enco = out + (size_t)B_ROWS * 7;
    float* outo = out + (size_t)B_ROWS * 37;

#pragma unroll
    for (int j = 0; j < 30; j++) enco[(size_t)b * 30 + j] = enc[j];

#pragma unroll
    for (int k = 0; k < 30; k++) r[k] = gelu_exact(enc[k]);
#pragma unroll
    for (int j = 0; j < 60; j++) {
        float a = sbd[j];
#pragma unroll
        for (int k = 0; k < 30; k++) a += r[k] * sWd[k * 60 + j];
        outo[(size_t)b * 60 + j] = a;
    }
#pragma unroll
    for (int j = 0; j < 7; j++) {
        float a = sbr[j];
#pragma unroll
        for (int k = 0; k < 30; k++) a += enc[k] * sWr[k * 7 + j];
        x1o[(size_t)b * 7 + j] = a;
    }
}

extern "C" void kernel_launch(void* const* d_in, const int* in_sizes, int n_in,
                              void* d_out, int out_size, void* d_ws, size_t ws_size,
                              hipStream_t stream) {
    const float* x   = (const float*)d_in[0];
    const int*   ei  = (const int*)d_in[1];
    const int*   src = ei;
    const int*   dst = ei + N_EDGES;
    const float* W1  = (const float*)d_in[2];
    const float* b1  = (const float*)d_in[3];
    const float* W2  = (const float*)d_in[4];
    const float* b2  = (const float*)d_in[5];
    const float* We  = (const float*)d_in[6];
    const float* be  = (const float*)d_in[7];
    const float* Wd  = (const float*)d_in[8];
    const float* bd  = (const float*)d_in[9];
    const float* Wr  = (const float*)d_in[10];
    const float* br  = (const float*)d_in[11];

    char* ws = (char*)d_ws;
    // epack (48 MB) consumed by k_bbuild, then reused as hs2p (38.4 MB).
    unsigned int* epack = (unsigned int*)ws;  ws += sizeof(unsigned int) * (size_t)N_EDGES;
    float* hs2p  = (float*)epack;
    int*   csr    = (int*)ws;   ws += sizeof(int) * (size_t)N_EDGES;
    int*   rowptr = (int*)ws;   ws += sizeof(int) * (N_NODES + 16);
    float* dinv   = (float*)ws; ws += sizeof(float) * N_NODES;
    float* xs     = (float*)ws; ws += sizeof(float) * (size_t)N_NODES * PADX;
    float* h2     = (float*)ws; ws += sizeof(float) * (size_t)N_NODES * D_ENCC;
    int*   hist   = (int*)ws;   ws += sizeof(int) * (size_t)NBLK_E * NBUCK;
    int*   gcount = (int*)ws;   ws += sizeof(int) * NBUCK;
    int*   bstart = (int*)ws;   ws += sizeof(int) * (NBUCK + 16);
    int*   bcursor= (int*)ws;   ws += sizeof(int) * NBUCK;

    hipMemsetAsync(gcount, 0, sizeof(int) * NBUCK, stream);

    k_bhist   <<<NBLK_E, 256, 0, stream>>>(dst, gcount, hist);
    k_bscan   <<<1, 256, 0, stream>>>(gcount, bstart, bcursor);
    k_bscatter<<<NBLK_E, 1024, 0, stream>>>(src, dst, hist, bcursor, epack);
    k_bbuild  <<<NBUCK, 256, 0, stream>>>(epack, bstart, x, csr, rowptr, dinv, xs);
    k_agg1    <<<(int)(((long)N_NODES * 5) / 320), 320, 0, stream>>>(rowptr, csr, xs,
                                                                     dinv, W1, b1, W2, hs2p);
    k_agg2    <<<(int)(((long)N_NODES * 5 + 255) / 256), 256, 0, stream>>>(rowptr, csr,
                                                                           hs2p, dinv, b2, h2);
    k_dense   <<<(B_ROWS + 255) / 256, 256, 0, stream>>>(h2, We, be, Wd, bd, Wr, br,
                                                         (float*)d_out);
}